// Round 2
// baseline (1056.774 us; speedup 1.0000x reference)
//
#include <hip/hip_runtime.h>

typedef unsigned short ushort_t;
typedef unsigned int uint_t;

__device__ __forceinline__ float bf_lo(uint_t w) { return __uint_as_float(w << 16); }
__device__ __forceinline__ float bf_hi(uint_t w) { return __uint_as_float(w & 0xFFFF0000u); }
__device__ __forceinline__ float bf2f(ushort_t u) { return __uint_as_float(((uint_t)u) << 16); }
__device__ __forceinline__ ushort_t f2bf(float f) {
    uint_t u = __float_as_uint(f);
    u += 0x7FFFu + ((u >> 16) & 1u);
    return (ushort_t)(u >> 16);
}
__device__ __forceinline__ float sigm(float x) { return 1.0f / (1.0f + __expf(-x)); }
__device__ __forceinline__ float tanhx(float x) {
    x = fminf(fmaxf(x, -15.0f), 15.0f);
    float e = __expf(2.0f * x);
    return (e - 1.0f) / (e + 1.0f);
}

// Pack fp32 weights -> bf16, transposed + grouped-by-8 along K:
// element (k, v) of the K-major transposed matrix goes to
// dst[((k>>3)*V + v)*8 + (k&7)], so a thread indexed by gate v loads 8
// consecutive k's as one coalesced dwordx4. k >= KA+KB pads with 0.
__global__ void pack_w(const float* __restrict__ srcA, int KA,
                       const float* __restrict__ srcB, int KB,
                       ushort_t* __restrict__ dst, int V, int Kpad)
{
    int idx = blockIdx.x * 256 + threadIdx.x;
    if (idx >= V * Kpad) return;
    int v = idx / Kpad;
    int k = idx - v * Kpad;
    float val = 0.0f;
    if (k < KA) val = srcA[v * KA + k];
    else if (k < KA + KB) val = srcB[v * KB + (k - KA)];
    dst[((k >> 3) * V + v) * 8 + (k & 7)] = f2bf(val);
}

// Phase A: time-LSTM with zero state == two feed-forward gated layers.
// f-gate is dead (c_prev = 0). Block = 16 rows x 256 gate-units.
__global__ __launch_bounds__(256) void phaseA(
    const float* __restrict__ note,
    const ushort_t* __restrict__ Wp0, const float* __restrict__ b0,
    const ushort_t* __restrict__ Wp1, const float* __restrict__ b1,
    ushort_t* __restrict__ feats)
{
    __shared__ __align__(16) float x0[56 * 16];    // [k][row], k-major, pad cols 50..55 zeroed
    __shared__ __align__(16) float h1s[256 * 16];  // [unit][row] == next layer's [k][row]
    const int tid = threadIdx.x;
    const int row0 = blockIdx.x * 16;

    // build the 50-feature input rows (pitch_pos | pitch_class | vicinity | chord)
    for (int idx = tid; idx < 16 * 56; idx += 256) {
        int r = idx / 56;
        int c = idx - r * 56;
        int row = row0 + r;
        int b = row / 48;
        int n = row - b * 48;
        float val = 0.0f;
        if (c == 0) val = (float)n * (1.0f / 48.0f);
        else if (c < 13) val = ((n % 12) == (c - 1)) ? 1.0f : 0.0f;
        else if (c < 38) {
            int p = n + (c - 13) - 12;
            if (p >= 0 && p < 48) val = note[b * 48 + p];
        } else if (c < 50) {
            const float* nb = note + b * 48 + (c - 38) * 4;
            val = nb[0] + nb[1] + nb[2] + nb[3];
        }
        x0[c * 16 + r] = val;
    }
    __syncthreads();

    float ai[16], ag[16], ao[16];
    float hv[16];
    {
        float bi = b0[tid], bg = b0[512 + tid], bo = b0[768 + tid];
#pragma unroll
        for (int r = 0; r < 16; ++r) { ai[r] = bi; ag[r] = bg; ao[r] = bo; }
    }
    // layer 0: K = 56 (padded), gates i/g/o for unit = tid
    for (int kg = 0; kg < 7; ++kg) {
        uint4 wiq = *(const uint4*)(Wp0 + (kg * 1024 + tid) * 8);
        uint4 wgq = *(const uint4*)(Wp0 + (kg * 1024 + 512 + tid) * 8);
        uint4 woq = *(const uint4*)(Wp0 + (kg * 1024 + 768 + tid) * 8);
        const uint_t* wi = (const uint_t*)&wiq;
        const uint_t* wg = (const uint_t*)&wgq;
        const uint_t* wo = (const uint_t*)&woq;
#pragma unroll
        for (int j = 0; j < 8; ++j) {
            uint_t wwi = wi[j >> 1], wwg = wg[j >> 1], wwo = wo[j >> 1];
            float fwi = (j & 1) ? bf_hi(wwi) : bf_lo(wwi);
            float fwg = (j & 1) ? bf_hi(wwg) : bf_lo(wwg);
            float fwo = (j & 1) ? bf_hi(wwo) : bf_lo(wwo);
            const float4* xp = (const float4*)&x0[(kg * 8 + j) * 16];
#pragma unroll
            for (int q = 0; q < 4; ++q) {
                float4 xv = xp[q];
                ai[q*4+0] += fwi * xv.x; ai[q*4+1] += fwi * xv.y; ai[q*4+2] += fwi * xv.z; ai[q*4+3] += fwi * xv.w;
                ag[q*4+0] += fwg * xv.x; ag[q*4+1] += fwg * xv.y; ag[q*4+2] += fwg * xv.z; ag[q*4+3] += fwg * xv.w;
                ao[q*4+0] += fwo * xv.x; ao[q*4+1] += fwo * xv.y; ao[q*4+2] += fwo * xv.z; ao[q*4+3] += fwo * xv.w;
            }
        }
    }
#pragma unroll
    for (int r = 0; r < 16; ++r) {
        float c = sigm(ai[r]) * tanhx(ag[r]);
        hv[r] = sigm(ao[r]) * tanhx(c);
    }
    // staggered write to break the 16-float stride conflict pattern
#pragma unroll
    for (int jj = 0; jj < 16; ++jj) {
        int r = (tid + jj) & 15;
        h1s[tid * 16 + r] = hv[r];
    }
    __syncthreads();

    {
        float bi = b1[tid], bg = b1[512 + tid], bo = b1[768 + tid];
#pragma unroll
        for (int r = 0; r < 16; ++r) { ai[r] = bi; ag[r] = bg; ao[r] = bo; }
    }
    // layer 1: K = 256
    for (int kg = 0; kg < 32; ++kg) {
        uint4 wiq = *(const uint4*)(Wp1 + (kg * 1024 + tid) * 8);
        uint4 wgq = *(const uint4*)(Wp1 + (kg * 1024 + 512 + tid) * 8);
        uint4 woq = *(const uint4*)(Wp1 + (kg * 1024 + 768 + tid) * 8);
        const uint_t* wi = (const uint_t*)&wiq;
        const uint_t* wg = (const uint_t*)&wgq;
        const uint_t* wo = (const uint_t*)&woq;
#pragma unroll
        for (int j = 0; j < 8; ++j) {
            uint_t wwi = wi[j >> 1], wwg = wg[j >> 1], wwo = wo[j >> 1];
            float fwi = (j & 1) ? bf_hi(wwi) : bf_lo(wwi);
            float fwg = (j & 1) ? bf_hi(wwg) : bf_lo(wwg);
            float fwo = (j & 1) ? bf_hi(wwo) : bf_lo(wwo);
            const float4* xp = (const float4*)&h1s[(kg * 8 + j) * 16];
#pragma unroll
            for (int q = 0; q < 4; ++q) {
                float4 xv = xp[q];
                ai[q*4+0] += fwi * xv.x; ai[q*4+1] += fwi * xv.y; ai[q*4+2] += fwi * xv.z; ai[q*4+3] += fwi * xv.w;
                ag[q*4+0] += fwg * xv.x; ag[q*4+1] += fwg * xv.y; ag[q*4+2] += fwg * xv.z; ag[q*4+3] += fwg * xv.w;
                ao[q*4+0] += fwo * xv.x; ao[q*4+1] += fwo * xv.y; ao[q*4+2] += fwo * xv.z; ao[q*4+3] += fwo * xv.w;
            }
        }
    }
#pragma unroll
    for (int r = 0; r < 16; ++r) {
        float c = sigm(ai[r]) * tanhx(ag[r]);
        float h2 = sigm(ao[r]) * tanhx(c);
        feats[(size_t)(row0 + r) * 256 + tid] = f2bf(h2);
    }
}

// Phase B: 48-step 2-layer LSTM scan. Batch rows are independent -> one
// persistent block per 4 rows, no grid sync. 512 threads = one gate each.
// c-states live in registers of the owning thread. 5 barriers / step.
__global__ __launch_bounds__(512) void phaseB(
    const ushort_t* __restrict__ feats, const float* __restrict__ targets,
    const ushort_t* __restrict__ N0p, const float* __restrict__ nb0,
    const ushort_t* __restrict__ N1p, const float* __restrict__ nb1,
    const float* __restrict__ outW, const float* __restrict__ outb,
    float* __restrict__ out)
{
    __shared__ __align__(16) float xt[392 * 4];   // layer1 in: [k][row]; k<256 feats, 256 cond, 257..384 h1, pad 0
    __shared__ __align__(16) float x2t[256 * 4];  // layer2 in: k<128 h1, 128..255 h2
    __shared__ __align__(16) float g_lds[512 * 4];
    __shared__ __align__(16) float ow[128];
    const int tid = threadIdx.x;
    const int r0 = blockIdx.x * 4;

    for (int idx = tid; idx < 392 * 4; idx += 512) xt[idx] = 0.0f;
    for (int idx = tid; idx < 256 * 4; idx += 512) x2t[idx] = 0.0f;
    if (tid < 128) ow[tid] = outW[tid];
    const float bias0 = nb0[tid];
    const float bias1 = nb1[tid];
    const float ob = outb[0];
    const int unit = tid >> 2;
    const int rr = tid & 3;
    float c1 = 0.0f, c2 = 0.0f;
    __syncthreads();

    for (int t = 0; t < 48; ++t) {
        // stage x = [feats | cond] transposed into LDS
        for (int idx = tid; idx < 1024; idx += 512) {
            int r = idx >> 8;
            int k = idx & 255;
            xt[k * 4 + r] = bf2f(feats[((size_t)(r0 + r) * 48 + t) * 256 + k]);
        }
        if (tid < 4) xt[256 * 4 + tid] = (t > 0) ? targets[(r0 + tid) * 48 + t - 1] : 0.0f;
        __syncthreads();

        // layer-1 gates: gate v = tid, K = 392 (257 x + 128 h1 + 7 pad)
        {
            float a0 = bias0, a1 = bias0, a2 = bias0, a3 = bias0;
            const uint4* wp = (const uint4*)(N0p) + tid;
            uint4 wq = wp[0];
            for (int kg = 0; kg < 49; ++kg) {
                uint4 wn = (kg < 48) ? wp[(kg + 1) * 512] : wq;  // 1-deep prefetch
                const uint_t* wu = (const uint_t*)&wq;
                const float4* xp = (const float4*)&xt[kg * 32];
#pragma unroll
                for (int jj = 0; jj < 4; ++jj) {
                    uint_t w = wu[jj];
                    float f0 = bf_lo(w), f1 = bf_hi(w);
                    float4 xa = xp[jj * 2], xb = xp[jj * 2 + 1];
                    a0 += f0 * xa.x; a1 += f0 * xa.y; a2 += f0 * xa.z; a3 += f0 * xa.w;
                    a0 += f1 * xb.x; a1 += f1 * xb.y; a2 += f1 * xb.z; a3 += f1 * xb.w;
                }
                wq = wn;
            }
            *(float4*)&g_lds[tid * 4] = make_float4(a0, a1, a2, a3);
        }
        __syncthreads();
        // layer-1 elementwise
        {
            float gi = g_lds[unit * 4 + rr];
            float gf = g_lds[(128 + unit) * 4 + rr];
            float gg = g_lds[(256 + unit) * 4 + rr];
            float go = g_lds[(384 + unit) * 4 + rr];
            c1 = sigm(gf) * c1 + sigm(gi) * tanhx(gg);
            float h1 = sigm(go) * tanhx(c1);
            xt[(257 + unit) * 4 + rr] = h1;
            x2t[unit * 4 + rr] = h1;
        }
        __syncthreads();
        // layer-2 gates: K = 256 (128 h1 + 128 h2)
        {
            float a0 = bias1, a1 = bias1, a2 = bias1, a3 = bias1;
            const uint4* wp = (const uint4*)(N1p) + tid;
            uint4 wq = wp[0];
            for (int kg = 0; kg < 32; ++kg) {
                uint4 wn = (kg < 31) ? wp[(kg + 1) * 512] : wq;
                const uint_t* wu = (const uint_t*)&wq;
                const float4* xp = (const float4*)&x2t[kg * 32];
#pragma unroll
                for (int jj = 0; jj < 4; ++jj) {
                    uint_t w = wu[jj];
                    float f0 = bf_lo(w), f1 = bf_hi(w);
                    float4 xa = xp[jj * 2], xb = xp[jj * 2 + 1];
                    a0 += f0 * xa.x; a1 += f0 * xa.y; a2 += f0 * xa.z; a3 += f0 * xa.w;
                    a0 += f1 * xb.x; a1 += f1 * xb.y; a2 += f1 * xb.z; a3 += f1 * xb.w;
                }
                wq = wn;
            }
            *(float4*)&g_lds[tid * 4] = make_float4(a0, a1, a2, a3);
        }
        __syncthreads();
        // layer-2 elementwise
        {
            float gi = g_lds[unit * 4 + rr];
            float gf = g_lds[(128 + unit) * 4 + rr];
            float gg = g_lds[(256 + unit) * 4 + rr];
            float go = g_lds[(384 + unit) * 4 + rr];
            c2 = sigm(gf) * c2 + sigm(gi) * tanhx(gg);
            float h2 = sigm(go) * tanhx(c2);
            x2t[(128 + unit) * 4 + rr] = h2;
        }
        __syncthreads();
        // output head: out[b][t] = sigmoid(h2 . outW + b), wave-per-row reduce
        if (tid < 256) {
            int r = tid >> 6;
            int l = tid & 63;
            float p = x2t[(128 + l) * 4 + r] * ow[l] + x2t[(192 + l) * 4 + r] * ow[64 + l];
#pragma unroll
            for (int off = 32; off > 0; off >>= 1) p += __shfl_down(p, off, 64);
            if (l == 0) out[(r0 + r) * 48 + t] = sigm(p + ob);
        }
        // next-t xt overwrite is safe: all xt readers passed the post-gate barrier
    }
}

extern "C" void kernel_launch(void* const* d_in, const int* in_sizes, int n_in,
                              void* d_out, int out_size, void* d_ws, size_t ws_size,
                              hipStream_t stream)
{
    const float* note  = (const float*)d_in[0];
    const float* targ  = (const float*)d_in[1];
    const float* tWih0 = (const float*)d_in[2];
    const float* tb0   = (const float*)d_in[4];
    const float* tWih1 = (const float*)d_in[5];
    const float* tb1   = (const float*)d_in[7];
    const float* nWih0 = (const float*)d_in[8];
    const float* nWhh0 = (const float*)d_in[9];
    const float* nb0   = (const float*)d_in[10];
    const float* nWih1 = (const float*)d_in[11];
    const float* nWhh1 = (const float*)d_in[12];
    const float* nb1   = (const float*)d_in[13];
    const float* outW  = (const float*)d_in[14];
    const float* outb  = (const float*)d_in[15];

    char* ws = (char*)d_ws;
    ushort_t* feats = (ushort_t*)(ws);               // 49152*256 bf16 = 25165824 B
    ushort_t* W0p   = (ushort_t*)(ws + 25165824);    // 56*1024  bf16 = 114688 B
    ushort_t* W1p   = (ushort_t*)(ws + 25280512);    // 256*1024 bf16 = 524288 B
    ushort_t* N0p   = (ushort_t*)(ws + 25804800);    // 392*512  bf16 = 401408 B
    ushort_t* N1p   = (ushort_t*)(ws + 26206208);    // 256*512  bf16 = 262144 B

    pack_w<<<(1024 * 56 + 255) / 256, 256, 0, stream>>>(tWih0, 50, (const float*)0, 0, W0p, 1024, 56);
    pack_w<<<(1024 * 256 + 255) / 256, 256, 0, stream>>>(tWih1, 256, (const float*)0, 0, W1p, 1024, 256);
    pack_w<<<(512 * 392 + 255) / 256, 256, 0, stream>>>(nWih0, 257, nWhh0, 128, N0p, 512, 392);
    pack_w<<<(512 * 256 + 255) / 256, 256, 0, stream>>>(nWih1, 128, nWhh1, 128, N1p, 512, 256);

    phaseA<<<3072, 256, 0, stream>>>(note, W0p, tb0, W1p, tb1, feats);
    phaseB<<<256, 512, 0, stream>>>(feats, targ, N0p, nb0, N1p, nb1, outW, outb, (float*)d_out);
}

// Round 3
// 746.404 us; speedup vs baseline: 1.4158x; 1.4158x over previous
//
#include <hip/hip_runtime.h>

typedef unsigned short ushort_t;
typedef unsigned int uint_t;
typedef _Float16 f16_t;
typedef _Float16 half2_t __attribute__((ext_vector_type(2)));

__device__ __forceinline__ float dot2(uint_t w, uint_t x, float acc) {
    return __builtin_amdgcn_fdot2(__builtin_bit_cast(half2_t, w),
                                  __builtin_bit_cast(half2_t, x), acc, false);
}
__device__ __forceinline__ ushort_t f2h_bits(float f) {
    f16_t h = (f16_t)f;
    return __builtin_bit_cast(ushort_t, h);
}
__device__ __forceinline__ float sigm(float x) { return 1.0f / (1.0f + __expf(-x)); }
__device__ __forceinline__ float tanhx(float x) {
    x = fminf(fmaxf(x, -15.0f), 15.0f);
    float e = __expf(2.0f * x);
    return (e - 1.0f) / (e + 1.0f);
}

// Pack fp32 weights -> f16, transposed + grouped-by-8 along K:
// element (k, v) -> dst[((k>>3)*V + v)*8 + (k&7)]. A thread indexed by gate v
// loads 8 consecutive k's (= 4 f16-pairs) as one dwordx4. k >= KA+KB pads 0.
__global__ void pack_w(const float* __restrict__ srcA, int KA,
                       const float* __restrict__ srcB, int KB,
                       ushort_t* __restrict__ dst, int V, int Kpad)
{
    int idx = blockIdx.x * 256 + threadIdx.x;
    if (idx >= V * Kpad) return;
    int v = idx / Kpad;
    int k = idx - v * Kpad;
    float val = 0.0f;
    if (k < KA) val = srcA[v * KA + k];
    else if (k < KA + KB) val = srcB[v * KB + (k - KA)];
    dst[((k >> 3) * V + v) * 8 + (k & 7)] = f2h_bits(val);
}

// Phase A: time-LSTM with zero state == two feed-forward gated layers
// (f-gate dead). Block = 16 rows x 256 gate-units; f16 dot2 datapath.
__global__ __launch_bounds__(256) void phaseA(
    const float* __restrict__ note,
    const ushort_t* __restrict__ Wp0, const float* __restrict__ b0,
    const ushort_t* __restrict__ Wp1, const float* __restrict__ b1,
    ushort_t* __restrict__ feats)
{
    __shared__ __align__(16) uint_t x0p[28 * 16];    // [kpair][row] f16 pairs, K=56
    __shared__ __align__(16) uint_t h1p[128 * 16];   // [kpair][row], 256 units
    ushort_t* x0us = (ushort_t*)x0p;
    ushort_t* h1us = (ushort_t*)h1p;
    const int tid = threadIdx.x;
    const int row0 = blockIdx.x * 16;

    // build the 50-feature input rows (pitch_pos | pitch_class | vicinity | chord)
    for (int idx = tid; idx < 16 * 56; idx += 256) {
        int r = idx / 56;
        int c = idx - r * 56;
        int row = row0 + r;
        int b = row / 48;
        int n = row - b * 48;
        float val = 0.0f;
        if (c == 0) val = (float)n * (1.0f / 48.0f);
        else if (c < 13) val = ((n % 12) == (c - 1)) ? 1.0f : 0.0f;
        else if (c < 38) {
            int p = n + (c - 13) - 12;
            if (p >= 0 && p < 48) val = note[b * 48 + p];
        } else if (c < 50) {
            const float* nb = note + b * 48 + (c - 38) * 4;
            val = nb[0] + nb[1] + nb[2] + nb[3];
        }
        x0us[(c >> 1) * 32 + r * 2 + (c & 1)] = f2h_bits(val);
    }
    __syncthreads();

    float ai[16], ag[16], ao[16];
    float hv[16];
    {
        float bi = b0[tid], bg = b0[512 + tid], bo = b0[768 + tid];
#pragma unroll
        for (int r = 0; r < 16; ++r) { ai[r] = bi; ag[r] = bg; ao[r] = bo; }
    }
    // layer 0: K = 56 (7 k-groups of 8)
    for (int kg = 0; kg < 7; ++kg) {
        uint4 wiq = *(const uint4*)(Wp0 + (kg * 1024 + tid) * 8);
        uint4 wgq = *(const uint4*)(Wp0 + (kg * 1024 + 512 + tid) * 8);
        uint4 woq = *(const uint4*)(Wp0 + (kg * 1024 + 768 + tid) * 8);
        const uint_t* wi = (const uint_t*)&wiq;
        const uint_t* wg = (const uint_t*)&wgq;
        const uint_t* wo = (const uint_t*)&woq;
#pragma unroll
        for (int jj = 0; jj < 4; ++jj) {
            uint_t wwi = wi[jj], wwg = wg[jj], wwo = wo[jj];
            const uint4* xp = (const uint4*)&x0p[(kg * 4 + jj) * 16];
#pragma unroll
            for (int q = 0; q < 4; ++q) {
                uint4 xv = xp[q];
                ai[q*4+0] = dot2(wwi, xv.x, ai[q*4+0]); ai[q*4+1] = dot2(wwi, xv.y, ai[q*4+1]);
                ai[q*4+2] = dot2(wwi, xv.z, ai[q*4+2]); ai[q*4+3] = dot2(wwi, xv.w, ai[q*4+3]);
                ag[q*4+0] = dot2(wwg, xv.x, ag[q*4+0]); ag[q*4+1] = dot2(wwg, xv.y, ag[q*4+1]);
                ag[q*4+2] = dot2(wwg, xv.z, ag[q*4+2]); ag[q*4+3] = dot2(wwg, xv.w, ag[q*4+3]);
                ao[q*4+0] = dot2(wwo, xv.x, ao[q*4+0]); ao[q*4+1] = dot2(wwo, xv.y, ao[q*4+1]);
                ao[q*4+2] = dot2(wwo, xv.z, ao[q*4+2]); ao[q*4+3] = dot2(wwo, xv.w, ao[q*4+3]);
            }
        }
    }
#pragma unroll
    for (int r = 0; r < 16; ++r) {
        float c = sigm(ai[r]) * tanhx(ag[r]);
        hv[r] = sigm(ao[r]) * tanhx(c);
    }
    // packed f16 h1 write; r swizzled by unit-pair to spread banks
#pragma unroll
    for (int jj = 0; jj < 16; ++jj) {
        int r = (jj + (tid >> 1)) & 15;
        h1us[(tid >> 1) * 32 + r * 2 + (tid & 1)] = f2h_bits(hv[r]);
    }
    __syncthreads();

    {
        float bi = b1[tid], bg = b1[512 + tid], bo = b1[768 + tid];
#pragma unroll
        for (int r = 0; r < 16; ++r) { ai[r] = bi; ag[r] = bg; ao[r] = bo; }
    }
    // layer 1: K = 256 (32 k-groups)
    for (int kg = 0; kg < 32; ++kg) {
        uint4 wiq = *(const uint4*)(Wp1 + (kg * 1024 + tid) * 8);
        uint4 wgq = *(const uint4*)(Wp1 + (kg * 1024 + 512 + tid) * 8);
        uint4 woq = *(const uint4*)(Wp1 + (kg * 1024 + 768 + tid) * 8);
        const uint_t* wi = (const uint_t*)&wiq;
        const uint_t* wg = (const uint_t*)&wgq;
        const uint_t* wo = (const uint_t*)&woq;
#pragma unroll
        for (int jj = 0; jj < 4; ++jj) {
            uint_t wwi = wi[jj], wwg = wg[jj], wwo = wo[jj];
            const uint4* xp = (const uint4*)&h1p[(kg * 4 + jj) * 16];
#pragma unroll
            for (int q = 0; q < 4; ++q) {
                uint4 xv = xp[q];
                ai[q*4+0] = dot2(wwi, xv.x, ai[q*4+0]); ai[q*4+1] = dot2(wwi, xv.y, ai[q*4+1]);
                ai[q*4+2] = dot2(wwi, xv.z, ai[q*4+2]); ai[q*4+3] = dot2(wwi, xv.w, ai[q*4+3]);
                ag[q*4+0] = dot2(wwg, xv.x, ag[q*4+0]); ag[q*4+1] = dot2(wwg, xv.y, ag[q*4+1]);
                ag[q*4+2] = dot2(wwg, xv.z, ag[q*4+2]); ag[q*4+3] = dot2(wwg, xv.w, ag[q*4+3]);
                ao[q*4+0] = dot2(wwo, xv.x, ao[q*4+0]); ao[q*4+1] = dot2(wwo, xv.y, ao[q*4+1]);
                ao[q*4+2] = dot2(wwo, xv.z, ao[q*4+2]); ao[q*4+3] = dot2(wwo, xv.w, ao[q*4+3]);
            }
        }
    }
#pragma unroll
    for (int r = 0; r < 16; ++r) {
        float c = sigm(ai[r]) * tanhx(ag[r]);
        float h2 = sigm(ao[r]) * tanhx(c);
        feats[(size_t)(row0 + r) * 256 + tid] = f2h_bits(h2);  // f16 bits
    }
}

// Phase B: 48-step 2-layer LSTM scan. One persistent block per 4 batch rows,
// 512 threads = one gate each; f16 dot2 datapath; c-states in registers.
__global__ __launch_bounds__(512) void phaseB(
    const ushort_t* __restrict__ feats, const float* __restrict__ targets,
    const ushort_t* __restrict__ N0p, const float* __restrict__ nb0,
    const ushort_t* __restrict__ N1p, const float* __restrict__ nb1,
    const float* __restrict__ outW, const float* __restrict__ outb,
    float* __restrict__ out)
{
    __shared__ __align__(16) uint_t xtp[196 * 4];   // K=392 f16 pairs: 256 feats,1 cond,128 h1,7 pad
    __shared__ __align__(16) uint_t x2p[128 * 4];   // K=256: 128 h1, 128 h2
    __shared__ __align__(16) float g_lds[512 * 4];
    __shared__ __align__(16) uint_t owp[64];
    ushort_t* xtus = (ushort_t*)xtp;
    ushort_t* x2us = (ushort_t*)x2p;
    const int tid = threadIdx.x;
    const int r0 = blockIdx.x * 4;

    for (int idx = tid; idx < 196 * 4; idx += 512) xtp[idx] = 0;   // zero pads + h1
    for (int idx = tid; idx < 128 * 4; idx += 512) x2p[idx] = 0;   // zero h1,h2 state
    if (tid < 64) {
        uint_t lo = f2h_bits(outW[2 * tid]);
        uint_t hi = f2h_bits(outW[2 * tid + 1]);
        owp[tid] = lo | (hi << 16);
    }
    const float bias0 = nb0[tid];
    const float bias1 = nb1[tid];
    const float ob = outb[0];
    const int unit = tid >> 2;
    const int rr = tid & 3;
    float c1 = 0.0f, c2 = 0.0f;
    __syncthreads();

    for (int t = 0; t < 48; ++t) {
        // stage feats (already f16 pairs) into xtp[p][row]
        {
            int p = tid & 127;
            int r = tid >> 7;
            xtp[p * 4 + r] = *(const uint_t*)&feats[((size_t)(r0 + r) * 48 + t) * 256 + 2 * p];
        }
        if (tid < 4) xtus[128 * 8 + tid * 2] =
            f2h_bits((t > 0) ? targets[(r0 + tid) * 48 + t - 1] : 0.0f);
        __syncthreads();

        // layer-1 gates: gate v = tid, K = 392 (49 k-groups)
        {
            float a0 = bias0, a1 = bias0, a2 = bias0, a3 = bias0;
            const uint4* wp = (const uint4*)(N0p) + tid;
            uint4 wq = wp[0];
            for (int kg = 0; kg < 49; ++kg) {
                uint4 wn = (kg < 48) ? wp[(kg + 1) * 512] : wq;  // 1-deep prefetch
                const uint_t* wu = (const uint_t*)&wq;
                const uint4* xp = (const uint4*)&xtp[kg * 16];
#pragma unroll
                for (int jj = 0; jj < 4; ++jj) {
                    uint_t w = wu[jj];
                    uint4 xv = xp[jj];
                    a0 = dot2(w, xv.x, a0);
                    a1 = dot2(w, xv.y, a1);
                    a2 = dot2(w, xv.z, a2);
                    a3 = dot2(w, xv.w, a3);
                }
                wq = wn;
            }
            *(float4*)&g_lds[tid * 4] = make_float4(a0, a1, a2, a3);
        }
        __syncthreads();
        // layer-1 elementwise; write h1 (f16) into xtp (k=257+unit) and x2p (k=unit)
        {
            float gi = g_lds[unit * 4 + rr];
            float gf = g_lds[(128 + unit) * 4 + rr];
            float gg = g_lds[(256 + unit) * 4 + rr];
            float go = g_lds[(384 + unit) * 4 + rr];
            c1 = sigm(gf) * c1 + sigm(gi) * tanhx(gg);
            float h1 = sigm(go) * tanhx(c1);
            ushort_t hb = f2h_bits(h1);
            int k1 = 257 + unit;
            xtus[(k1 >> 1) * 8 + rr * 2 + (k1 & 1)] = hb;
            x2us[(unit >> 1) * 8 + rr * 2 + (unit & 1)] = hb;
        }
        __syncthreads();
        // layer-2 gates: K = 256 (32 k-groups)
        {
            float a0 = bias1, a1 = bias1, a2 = bias1, a3 = bias1;
            const uint4* wp = (const uint4*)(N1p) + tid;
            uint4 wq = wp[0];
            for (int kg = 0; kg < 32; ++kg) {
                uint4 wn = (kg < 31) ? wp[(kg + 1) * 512] : wq;
                const uint_t* wu = (const uint_t*)&wq;
                const uint4* xp = (const uint4*)&x2p[kg * 16];
#pragma unroll
                for (int jj = 0; jj < 4; ++jj) {
                    uint_t w = wu[jj];
                    uint4 xv = xp[jj];
                    a0 = dot2(w, xv.x, a0);
                    a1 = dot2(w, xv.y, a1);
                    a2 = dot2(w, xv.z, a2);
                    a3 = dot2(w, xv.w, a3);
                }
                wq = wn;
            }
            *(float4*)&g_lds[tid * 4] = make_float4(a0, a1, a2, a3);
        }
        __syncthreads();
        // layer-2 elementwise; write h2 (f16) into x2p (k=128+unit)
        {
            float gi = g_lds[unit * 4 + rr];
            float gf = g_lds[(128 + unit) * 4 + rr];
            float gg = g_lds[(256 + unit) * 4 + rr];
            float go = g_lds[(384 + unit) * 4 + rr];
            c2 = sigm(gf) * c2 + sigm(gi) * tanhx(gg);
            float h2 = sigm(go) * tanhx(c2);
            x2us[(64 + (unit >> 1)) * 8 + rr * 2 + (unit & 1)] = f2h_bits(h2);
        }
        __syncthreads();
        // output head: dot2 over h2 pairs, wave-per-row shuffle reduce
        if (tid < 256) {
            int r = tid >> 6;
            int l = tid & 63;
            float p = dot2(owp[l], x2p[(64 + l) * 4 + r], 0.0f);
#pragma unroll
            for (int off = 32; off > 0; off >>= 1) p += __shfl_down(p, off, 64);
            if (l == 0) out[(r0 + r) * 48 + t] = sigm(p + ob);
        }
    }
}

extern "C" void kernel_launch(void* const* d_in, const int* in_sizes, int n_in,
                              void* d_out, int out_size, void* d_ws, size_t ws_size,
                              hipStream_t stream)
{
    const float* note  = (const float*)d_in[0];
    const float* targ  = (const float*)d_in[1];
    const float* tWih0 = (const float*)d_in[2];
    const float* tb0   = (const float*)d_in[4];
    const float* tWih1 = (const float*)d_in[5];
    const float* tb1   = (const float*)d_in[7];
    const float* nWih0 = (const float*)d_in[8];
    const float* nWhh0 = (const float*)d_in[9];
    const float* nb0   = (const float*)d_in[10];
    const float* nWih1 = (const float*)d_in[11];
    const float* nWhh1 = (const float*)d_in[12];
    const float* nb1   = (const float*)d_in[13];
    const float* outW  = (const float*)d_in[14];
    const float* outb  = (const float*)d_in[15];

    char* ws = (char*)d_ws;
    ushort_t* feats = (ushort_t*)(ws);               // 49152*256 f16 = 25165824 B
    ushort_t* W0p   = (ushort_t*)(ws + 25165824);    // 56*1024  = 114688 B
    ushort_t* W1p   = (ushort_t*)(ws + 25280512);    // 256*1024 = 524288 B
    ushort_t* N0p   = (ushort_t*)(ws + 25804800);    // 392*512  = 401408 B
    ushort_t* N1p   = (ushort_t*)(ws + 26206208);    // 256*512  = 262144 B

    pack_w<<<(1024 * 56 + 255) / 256, 256, 0, stream>>>(tWih0, 50, (const float*)0, 0, W0p, 1024, 56);
    pack_w<<<(1024 * 256 + 255) / 256, 256, 0, stream>>>(tWih1, 256, (const float*)0, 0, W1p, 1024, 256);
    pack_w<<<(512 * 392 + 255) / 256, 256, 0, stream>>>(nWih0, 257, nWhh0, 128, N0p, 512, 392);
    pack_w<<<(512 * 256 + 255) / 256, 256, 0, stream>>>(nWih1, 128, nWhh1, 128, N1p, 512, 256);

    phaseA<<<3072, 256, 0, stream>>>(note, W0p, tb0, W1p, tb1, feats);
    phaseB<<<256, 512, 0, stream>>>(feats, targ, N0p, nb0, N1p, nb1, outW, outb, (float*)d_out);
}